// Round 6
// baseline (7567.593 us; speedup 1.0000x reference)
//
#include <hip/hip_runtime.h>
#include <hip/hip_cooperative_groups.h>

namespace cg = cooperative_groups;

// Problem constants (reference: N=2048, A=100)
#define NN 2048
#define AA 100
#define NT 32   // 64-wide tiles per side (2048/64)
#define FW_INF __builtin_huge_valf()

// ---------------------------------------------------------------------------
// Shared device helpers. dist is ALWAYS 16B-aligned (see kernel_launch), so
// tile staging, C-block loads and stores are all float4.
// ---------------------------------------------------------------------------
__device__ __forceinline__ void stage_tile(const float* __restrict__ g, int base,
                                           float (*S)[68], int t) {
#pragma unroll
  for (int l = 0; l < 4; ++l) {
    int i4 = l * 256 + t;                   // 0..1023 = 64 rows x 16 float4
    int row = i4 >> 4, c4 = (i4 & 15) << 2;
    *(float4*)&S[row][c4] = *(const float4*)&g[base + row * NN + c4];
  }
}

__device__ __forceinline__ void load_c(const float* __restrict__ g, int base,
                                       float c[4][4], int i0, int j0) {
#pragma unroll
  for (int ii = 0; ii < 4; ++ii) {
    float4 v = *(const float4*)&g[base + (i0 + ii) * NN + j0];
    c[ii][0] = v.x; c[ii][1] = v.y; c[ii][2] = v.z; c[ii][3] = v.w;
  }
}

__device__ __forceinline__ void store_c(float* __restrict__ g, int base,
                                        const float c[4][4], int i0, int j0) {
#pragma unroll
  for (int ii = 0; ii < 4; ++ii)
    *(float4*)&g[base + (i0 + ii) * NN + j0] =
        make_float4(c[ii][0], c[ii][1], c[ii][2], c[ii][3]);
}

// k4 min-plus inner loop: c = min(c, A(i0-rows) (x) B(j0-cols)), k=0..63.
// All LDS reads are b128 (2 per k per thread).
__device__ __forceinline__ void minplus16(const float (*A)[68], const float (*B)[68],
                                          float c[4][4], int i0, int j0) {
#pragma unroll 4
  for (int k4 = 0; k4 < 16; ++k4) {
    const int k = k4 * 4;
    float4 a0 = *(const float4*)&A[i0 + 0][k];
    float4 a1 = *(const float4*)&A[i0 + 1][k];
    float4 a2 = *(const float4*)&A[i0 + 2][k];
    float4 a3 = *(const float4*)&A[i0 + 3][k];
    float4 b0 = *(const float4*)&B[k + 0][j0];
    float4 b1 = *(const float4*)&B[k + 1][j0];
    float4 b2 = *(const float4*)&B[k + 2][j0];
    float4 b3 = *(const float4*)&B[k + 3][j0];
#define MP_ROW(ii)                                                                        \
    c[ii][0] = fminf(c[ii][0], fminf(fminf(a##ii.x + b0.x, a##ii.y + b1.x),               \
                                     fminf(a##ii.z + b2.x, a##ii.w + b3.x)));             \
    c[ii][1] = fminf(c[ii][1], fminf(fminf(a##ii.x + b0.y, a##ii.y + b1.y),               \
                                     fminf(a##ii.z + b2.y, a##ii.w + b3.y)));             \
    c[ii][2] = fminf(c[ii][2], fminf(fminf(a##ii.x + b0.z, a##ii.y + b1.z),               \
                                     fminf(a##ii.z + b2.z, a##ii.w + b3.z)));             \
    c[ii][3] = fminf(c[ii][3], fminf(fminf(a##ii.x + b0.w, a##ii.y + b1.w),               \
                                     fminf(a##ii.z + b2.w, a##ii.w + b3.w)))
    MP_ROW(0); MP_ROW(1); MP_ROW(2); MP_ROW(3);
#undef MP_ROW
  }
}

// In-place transitive closure of the 64x64 tile in S (c == S's (i0,j0) block,
// staged & barriered by caller). 6 in-place squaring passes; min-monotone
// mid-pass races are safe (4B LDS atomicity, values are always real path
// lengths, only decrease). On exit c (and S) hold the closed tile.
__device__ __forceinline__ void close_in_lds(float (*S)[68], float c[4][4],
                                             int i0, int j0) {
  for (int p = 0; p < 6; ++p) {
    minplus16(S, S, c, i0, j0);
#pragma unroll
    for (int ii = 0; ii < 4; ++ii)
      *(float4*)&S[i0 + ii][j0] = make_float4(c[ii][0], c[ii][1], c[ii][2], c[ii][3]);
    __syncthreads();
  }
}

// Phase-2 body: side 0: C(r,tile) = min(C, diag (x) C); side 1: C(tile,r) =
// min(C, C (x) diag). diag is transitively closed -> one-pass in-place valid.
__device__ __forceinline__ void p2_body(float* __restrict__ d, int r, int side,
                                        int tile, float (*As)[68], float (*Bs)[68],
                                        int t, int i0, int j0) {
  int dbase = (r * 64) * NN + r * 64;
  int obase = (side == 0) ? (r * 64) * NN + tile * 64
                          : (tile * 64) * NN + r * 64;
  stage_tile(d, dbase, (side == 0) ? As : Bs, t);   // diag -> A op (side0) / B op (side1)
  stage_tile(d, obase, (side == 0) ? Bs : As, t);   // own
  float c[4][4];
  load_c(d, obase, c, i0, j0);
  __syncthreads();
  minplus16(As, Bs, c, i0, j0);
  store_c(d, obase, c, i0, j0);
}

// Phase-3 body: C(by,bx) = min(C, (by,r) (x) (r,bx)); optional fused closure
// (the block that owns next round's diagonal closes it before storing).
__device__ __forceinline__ void p3_body(float* __restrict__ d, int r, int by, int bx,
                                        bool do_close, float (*As)[68], float (*Bs)[68],
                                        int t, int i0, int j0) {
  stage_tile(d, (by * 64) * NN + r * 64, As, t);
  stage_tile(d, (r * 64) * NN + bx * 64, Bs, t);
  int obase = (by * 64) * NN + bx * 64;
  float c[4][4];
  load_c(d, obase, c, i0, j0);
  __syncthreads();
  minplus16(As, Bs, c, i0, j0);
  if (do_close) {
    __syncthreads();   // all As/Bs reads of the minplus done
#pragma unroll
    for (int ii = 0; ii < 4; ++ii)
      *(float4*)&As[i0 + ii][j0] = make_float4(c[ii][0], c[ii][1], c[ii][2], c[ii][3]);
    __syncthreads();
    close_in_lds(As, c, i0, j0);
  }
  store_c(d, obase, c, i0, j0);
}

// ---------------------------------------------------------------------------
// MEGA: whole blocked FW in ONE cooperative kernel. Grid must be exactly 1024
// blocks (4/CU by LDS: 2*64*68*4 = 34816 B/block). grid.sync() between phases
// replaces 65 kernel launches -> no launch gaps, no DVFS idle-clock collapse.
// ---------------------------------------------------------------------------
__global__ __launch_bounds__(256, 4) void fw_mega(const float* __restrict__ mg,
                                                  const float* __restrict__ nw,
                                                  float* __restrict__ d) {
  cg::grid_group grid = cg::this_grid();
  __shared__ __align__(16) float As[64][68];
  __shared__ __align__(16) float Bs[64][68];
  const int t = threadIdx.x;
  const int bid = blockIdx.x;
  const int tx = t & 15, ty = t >> 4;
  const int i0 = ty * 4, j0 = tx * 4;

  // ---- build w: block bid -> tile (bi,bj); transpose element via LDS.
  {
    int bi = bid >> 5, bj = bid & 31;
#pragma unroll
    for (int l = 0; l < 16; ++l) {
      int idx = l * 256 + t;
      int rr = idx >> 6, cc = idx & 63;
      As[cc][rr] = mg[(bj * 64 + rr) * NN + bi * 64 + cc];   // = mg[j][i] transposed
    }
    __syncthreads();
#pragma unroll
    for (int l = 0; l < 16; ++l) {
      int idx = l * 256 + t;
      int rr = idx >> 6, cc = idx & 63;
      int i = bi * 64 + rr, j = bj * 64 + cc;
      float a = mg[i * NN + j] * nw[i];
      float b = As[rr][cc] * nw[j];
      float wa = a > 0.0f ? a : FW_INF;
      float wb = b > 0.0f ? b : FW_INF;
      float v = fminf(wa, wb);
      if (i == j) v = 0.0f;
      d[i * NN + j] = v;
    }
    __syncthreads();
  }
  grid.sync();

  // ---- close tile (0,0)
  if (bid == 0) {
    stage_tile(d, 0, As, t);
    float c[4][4];
    __syncthreads();
#pragma unroll
    for (int ii = 0; ii < 4; ++ii) {
      float4 v = *(const float4*)&As[i0 + ii][j0];
      c[ii][0] = v.x; c[ii][1] = v.y; c[ii][2] = v.z; c[ii][3] = v.w;
    }
    close_in_lds(As, c, i0, j0);
    store_c(d, 0, c, i0, j0);
  }
  grid.sync();

  // ---- 32 rounds of {p2 cross, p3 bulk + fused next-diag closure}
  for (int r = 0; r < NT; ++r) {
    if (bid < 62) {
      int side = bid & 1, idx = bid >> 1;      // 31 tiles x 2 sides
      int tile = idx + (idx >= r);             // skip r
      p2_body(d, r, side, tile, As, Bs, t, i0, j0);
    }
    grid.sync();
    {
      int by = bid >> 5, bx = bid & 31;
      if (by != r && bx != r) {
        bool closer = (by == r + 1) && (bx == r + 1) && (r + 1 < NT);
        p3_body(d, r, by, bx, closer, As, Bs, t, i0, j0);
      }
    }
    grid.sync();
  }
}

// ---------------------------------------------------------------------------
// Fallback path (used only if the cooperative launch is rejected): same
// bodies, one kernel per phase per round.
// ---------------------------------------------------------------------------
__global__ __launch_bounds__(256) void build_w_kernel(
    const float* __restrict__ mg, const float* __restrict__ nw,
    float* __restrict__ w) {
  __shared__ float Tt[64][65];
  int bi = blockIdx.y, bj = blockIdx.x;
  int t = threadIdx.x;
#pragma unroll
  for (int l = 0; l < 16; ++l) {
    int idx = l * 256 + t;
    int r = idx >> 6, c = idx & 63;
    Tt[c][r] = mg[(bj * 64 + r) * NN + bi * 64 + c];
  }
  __syncthreads();
#pragma unroll
  for (int l = 0; l < 16; ++l) {
    int idx = l * 256 + t;
    int r = idx >> 6, c = idx & 63;
    int i = bi * 64 + r, j = bj * 64 + c;
    float a = mg[i * NN + j] * nw[i];
    float b = Tt[r][c] * nw[j];
    float wa = a > 0.0f ? a : FW_INF;
    float wb = b > 0.0f ? b : FW_INF;
    float v = fminf(wa, wb);
    if (i == j) v = 0.0f;
    w[i * NN + j] = v;
  }
}

__global__ __launch_bounds__(256) void fw_close0(float* __restrict__ d) {
  __shared__ __align__(16) float As[64][68];
  int t = threadIdx.x;
  int tx = t & 15, ty = t >> 4;
  int i0 = ty * 4, j0 = tx * 4;
  stage_tile(d, 0, As, t);
  __syncthreads();
  float c[4][4];
#pragma unroll
  for (int ii = 0; ii < 4; ++ii) {
    float4 v = *(const float4*)&As[i0 + ii][j0];
    c[ii][0] = v.x; c[ii][1] = v.y; c[ii][2] = v.z; c[ii][3] = v.w;
  }
  close_in_lds(As, c, i0, j0);
  store_c(d, 0, c, i0, j0);
}

__global__ __launch_bounds__(256) void fw_p2(float* __restrict__ d, int r) {
  __shared__ __align__(16) float As[64][68];
  __shared__ __align__(16) float Bs[64][68];
  int t = threadIdx.x;
  int tx = t & 15, ty = t >> 4;
  int side = blockIdx.x & 1, idx = blockIdx.x >> 1;
  int tile = idx + (idx >= r);
  p2_body(d, r, side, tile, As, Bs, t, ty * 4, tx * 4);
}

__global__ __launch_bounds__(256) void fw_p3(float* __restrict__ d, int r) {
  __shared__ __align__(16) float As[64][68];
  __shared__ __align__(16) float Bs[64][68];
  int bx = blockIdx.x, by = blockIdx.y;
  if (bx == r || by == r) return;
  int t = threadIdx.x;
  int tx = t & 15, ty = t >> 4;
  bool closer = (bx == r + 1) && (by == r + 1) && (r + 1 < NT);
  p3_body(d, r, by, bx, closer, As, Bs, t, ty * 4, tx * 4);
}

// ---------------------------------------------------------------------------
// anchors[rank] = i, rank = #{j: nw[j]>nw[i]} + #{j<i: nw[j]==nw[i]}  (stable
// argsort(-nw)). nw staged in LDS, row scan split 4 ways.
// ---------------------------------------------------------------------------
__global__ __launch_bounds__(256) void anchors_kernel(
    const float* __restrict__ nw, int* __restrict__ anchors) {
  __shared__ __align__(16) float s[NN];
  int t = threadIdx.x;
#pragma unroll
  for (int l = 0; l < NN / 256; ++l) s[l * 256 + t] = nw[l * 256 + t];
  __syncthreads();
  int i = blockIdx.x * 64 + (t >> 2);
  int q = t & 3;
  float wi = s[i];
  int rank = 0;
  int jb = q * (NN / 4);
  for (int j = jb; j < jb + NN / 4; j += 4) {
    float4 v = *(const float4*)&s[j];
    rank += (int)(v.x > wi) + ((int)(v.x == wi) & (int)(j + 0 < i));
    rank += (int)(v.y > wi) + ((int)(v.y == wi) & (int)(j + 1 < i));
    rank += (int)(v.z > wi) + ((int)(v.z == wi) & (int)(j + 2 < i));
    rank += (int)(v.w > wi) + ((int)(v.w == wi) & (int)(j + 3 < i));
  }
  rank += __shfl_xor(rank, 1);
  rank += __shfl_xor(rank, 2);
  if (q == 0 && rank < AA) anchors[rank] = i;
}

// ---------------------------------------------------------------------------
// Gather consensus_vectors (inf -> 100), accumulate global sum.
// ---------------------------------------------------------------------------
__global__ __launch_bounds__(256) void cv_kernel(
    const float* __restrict__ dist, const int* __restrict__ anchors,
    float* __restrict__ cv_out, float* __restrict__ sum_acc) {
  int idx = blockIdx.x * 256 + threadIdx.x;   // 800*256 == 204800 exactly
  int i = idx / 100, a = idx - i * 100;
  float dv = dist[i * NN + anchors[a]];
  if (isinf(dv)) dv = 100.0f;
  cv_out[idx] = dv;
  float v = dv;
#pragma unroll
  for (int off = 32; off > 0; off >>= 1) v += __shfl_down(v, off);
  __shared__ float sv[4];
  int lane = threadIdx.x & 63, w = threadIdx.x >> 6;
  if (lane == 0) sv[w] = v;
  __syncthreads();
  if (threadIdx.x == 0) atomicAdd(sum_acc, sv[0] + sv[1] + sv[2] + sv[3]);
}

// ---------------------------------------------------------------------------
// consensus_graph: weighted = wm*cv on the fly; per-row xx in-block; K=100
// f32 dot + RBF epilogue.
// ---------------------------------------------------------------------------
__global__ __launch_bounds__(256) void graph_kernel(
    const float* __restrict__ wm, const float* __restrict__ cv,
    const float* __restrict__ sigma, float* __restrict__ graph) {
  __shared__ __align__(16) float As[64][108];
  __shared__ __align__(16) float Bs[64][108];
  __shared__ float xs[64], ys[64];
  int bx = blockIdx.x, by = blockIdx.y;
  int t = threadIdx.x;
#pragma unroll
  for (int l = 0; l < 7; ++l) {
    int idx = l * 256 + t;
    if (idx < 1600) {                 // 64 rows * 25 float4
      int row = idx / 25, c4 = (idx - row * 25) * 4;
      float4 wa = *(const float4*)&wm[(by * 64 + row) * AA + c4];
      float4 ca = *(const float4*)&cv[(by * 64 + row) * AA + c4];
      *(float4*)&As[row][c4] =
          make_float4(wa.x * ca.x, wa.y * ca.y, wa.z * ca.z, wa.w * ca.w);
      float4 wb = *(const float4*)&wm[(bx * 64 + row) * AA + c4];
      float4 cb = *(const float4*)&cv[(bx * 64 + row) * AA + c4];
      *(float4*)&Bs[row][c4] =
          make_float4(wb.x * cb.x, wb.y * cb.y, wb.z * cb.z, wb.w * cb.w);
    }
  }
  __syncthreads();
  if (t < 64) {
    float s = 0.0f;
    for (int k4 = 0; k4 < 25; ++k4) {
      float4 q = *(const float4*)&As[t][k4 * 4];
      s += q.x * q.x + q.y * q.y + q.z * q.z + q.w * q.w;
    }
    xs[t] = s;
  } else if (t < 128) {
    int r = t - 64;
    float s = 0.0f;
    for (int k4 = 0; k4 < 25; ++k4) {
      float4 q = *(const float4*)&Bs[r][k4 * 4];
      s += q.x * q.x + q.y * q.y + q.z * q.z + q.w * q.w;
    }
    ys[r] = s;
  }
  __syncthreads();
  int tx = t & 15, ty = t >> 4;
  float acc[4][4] = {{0.0f}};
#pragma unroll 5
  for (int k4 = 0; k4 < 25; ++k4) {
    int k = k4 * 4;
    float4 a_[4], b_[4];
#pragma unroll
    for (int ii = 0; ii < 4; ++ii) a_[ii] = *(const float4*)&As[ty + 16 * ii][k];
#pragma unroll
    for (int jj = 0; jj < 4; ++jj) b_[jj] = *(const float4*)&Bs[tx + 16 * jj][k];
#pragma unroll
    for (int ii = 0; ii < 4; ++ii)
#pragma unroll
      for (int jj = 0; jj < 4; ++jj)
        acc[ii][jj] += a_[ii].x * b_[jj].x + a_[ii].y * b_[jj].y +
                       a_[ii].z * b_[jj].z + a_[ii].w * b_[jj].w;
  }
  float s = *sigma;
  float inv2s2 = 0.5f / (s * s);
#pragma unroll
  for (int ii = 0; ii < 4; ++ii) {
    int gi = by * 64 + ty + 16 * ii;
    float xi = xs[ty + 16 * ii];
#pragma unroll
    for (int jj = 0; jj < 4; ++jj) {
      int gj = bx * 64 + tx + 16 * jj;
      float sq = fmaxf(xi + ys[tx + 16 * jj] - 2.0f * acc[ii][jj], 0.0f);
      graph[gi * NN + gj] = __expf(-(sq * sq) * inv2s2);  // scalar: graph base 4B-aligned
    }
  }
}

__global__ void finalize_kernel(const float* __restrict__ sum_acc,
                                float* __restrict__ out) {
  if (threadIdx.x == 0)
    *out = (*sum_acc - 204800.0f) / 204800.0f;  // (sum - N*100) / (N*A)
}

// ---------------------------------------------------------------------------
extern "C" void kernel_launch(void* const* d_in, const int* in_sizes, int n_in,
                              void* d_out, int out_size, void* d_ws, size_t ws_size,
                              hipStream_t stream) {
  (void)in_sizes; (void)n_in; (void)out_size;
  const float* mg    = (const float*)d_in[0];
  const float* nw    = (const float*)d_in[1];
  const float* wm    = (const float*)d_in[2];
  const float* sigma = (const float*)d_in[3];
  float* out        = (float*)d_out;
  float* cv_out     = out;            // 2048*100
  float* scalar_out = out + 204800;   // 1
  float* graph_out  = out + 204801;   // 2048*2048

  float* W = (float*)d_ws;
  float* sum_acc = W;                 // 1 float
  int* anchors   = (int*)(W + 4);     // 100 ints
  float* dist;
  if (ws_size >= (size_t)(256 + (size_t)NN * NN) * sizeof(float)) {
    dist = W + 256;                   // 16 MB scratch, 16B-aligned
  } else {
    // Alias dist onto out+204800 (16B-aligned: 204800*4 % 16 == 0). Overlaps
    // scalar slot + graph region; cv_kernel extracts anchor columns BEFORE
    // graph_kernel overwrites, and finalize writes the scalar LAST.
    dist = out + 204800;              // 204800+NN*NN = 4399104 <= out_size ✓
  }

  hipMemsetAsync(sum_acc, 0, sizeof(float), stream);

  void* kargs[] = {(void*)&mg, (void*)&nw, (void*)&dist};
  hipError_t ce = hipLaunchCooperativeKernel((const void*)fw_mega, dim3(1024),
                                             dim3(256), kargs, 0, stream);
  if (ce != hipSuccess) {
    // Fallback: multi-launch blocked FW (identical math).
    build_w_kernel<<<dim3(NT, NT), 256, 0, stream>>>(mg, nw, dist);
    fw_close0<<<1, 256, 0, stream>>>(dist);
    for (int r = 0; r < NT; ++r) {
      fw_p2<<<62, 256, 0, stream>>>(dist, r);
      fw_p3<<<dim3(NT, NT), 256, 0, stream>>>(dist, r);
    }
  }

  anchors_kernel<<<NN / 64, 256, 0, stream>>>(nw, anchors);
  cv_kernel<<<800, 256, 0, stream>>>(dist, anchors, cv_out, sum_acc);
  graph_kernel<<<dim3(NT, NT), 256, 0, stream>>>(wm, cv_out, sigma, graph_out);
  finalize_kernel<<<1, 64, 0, stream>>>(sum_acc, scalar_out);
}

// Round 7
// 2732.027 us; speedup vs baseline: 2.7700x; 2.7700x over previous
//
#include <hip/hip_runtime.h>

// Problem constants (reference: N=2048, A=100)
#define NN 2048
#define AA 100
#define NT 32   // 64-wide tiles per side (2048/64)
#define FW_INF __builtin_huge_valf()

// ---------------------------------------------------------------------------
// Shared helpers. dist is ALWAYS 16B-aligned; LDS rows padded to 68 floats
// (b128 reads: a-reads 2-way, b-reads 2-way bank aliasing — free per m136).
// ---------------------------------------------------------------------------
__device__ __forceinline__ void stage_tile(const float* __restrict__ g, int base,
                                           float (*S)[68], int t) {
#pragma unroll
  for (int l = 0; l < 4; ++l) {
    int i4 = l * 256 + t;                   // 0..1023 = 64 rows x 16 float4
    int row = i4 >> 4, c4 = (i4 & 15) << 2;
    *(float4*)&S[row][c4] = *(const float4*)&g[base + row * NN + c4];
  }
}

__device__ __forceinline__ void store_c(float* __restrict__ g, int base,
                                        const float c[4][4], int i0, int j0) {
#pragma unroll
  for (int ii = 0; ii < 4; ++ii)
    *(float4*)&g[base + (i0 + ii) * NN + j0] =
        make_float4(c[ii][0], c[ii][1], c[ii][2], c[ii][3]);
}

// k4 min-plus inner loop: c = min(c, A(i0-rows) (x) B(j0-cols)), k=0..63.
__device__ __forceinline__ void minplus16(const float (*A)[68], const float (*B)[68],
                                          float c[4][4], int i0, int j0) {
#pragma unroll 4
  for (int k4 = 0; k4 < 16; ++k4) {
    const int k = k4 * 4;
    float4 a0 = *(const float4*)&A[i0 + 0][k];
    float4 a1 = *(const float4*)&A[i0 + 1][k];
    float4 a2 = *(const float4*)&A[i0 + 2][k];
    float4 a3 = *(const float4*)&A[i0 + 3][k];
    float4 b0 = *(const float4*)&B[k + 0][j0];
    float4 b1 = *(const float4*)&B[k + 1][j0];
    float4 b2 = *(const float4*)&B[k + 2][j0];
    float4 b3 = *(const float4*)&B[k + 3][j0];
#define MP_ROW(ii)                                                                        \
    c[ii][0] = fminf(c[ii][0], fminf(fminf(a##ii.x + b0.x, a##ii.y + b1.x),               \
                                     fminf(a##ii.z + b2.x, a##ii.w + b3.x)));             \
    c[ii][1] = fminf(c[ii][1], fminf(fminf(a##ii.x + b0.y, a##ii.y + b1.y),               \
                                     fminf(a##ii.z + b2.y, a##ii.w + b3.y)));             \
    c[ii][2] = fminf(c[ii][2], fminf(fminf(a##ii.x + b0.z, a##ii.y + b1.z),               \
                                     fminf(a##ii.z + b2.z, a##ii.w + b3.z)));             \
    c[ii][3] = fminf(c[ii][3], fminf(fminf(a##ii.x + b0.w, a##ii.y + b1.w),               \
                                     fminf(a##ii.z + b2.w, a##ii.w + b3.w)))
    MP_ROW(0); MP_ROW(1); MP_ROW(2); MP_ROW(3);
#undef MP_ROW
  }
}

__device__ __forceinline__ float sel4(float x0, float x1, float x2, float x3, int j) {
  return j == 0 ? x0 : (j == 1 ? x1 : (j == 2 ? x2 : x3));
}

// Exact in-tile FW closure (publish variant, verified in R2): Ts holds the
// tile, c == Ts's (i0,j0) block in regs. Per step k only col/row k+1 is
// republished, so step-k reads never race with writes. On exit c is closed.
__device__ __forceinline__ void close_publish(float (*Ts)[68], float c[4][4],
                                              int i0, int j0) {
  for (int k = 0; k < 64; ++k) {
    float a0 = Ts[i0 + 0][k], a1 = Ts[i0 + 1][k], a2 = Ts[i0 + 2][k], a3 = Ts[i0 + 3][k];
    float4 b = *(const float4*)&Ts[k][j0];
    c[0][0] = fminf(c[0][0], a0 + b.x); c[0][1] = fminf(c[0][1], a0 + b.y);
    c[0][2] = fminf(c[0][2], a0 + b.z); c[0][3] = fminf(c[0][3], a0 + b.w);
    c[1][0] = fminf(c[1][0], a1 + b.x); c[1][1] = fminf(c[1][1], a1 + b.y);
    c[1][2] = fminf(c[1][2], a1 + b.z); c[1][3] = fminf(c[1][3], a1 + b.w);
    c[2][0] = fminf(c[2][0], a2 + b.x); c[2][1] = fminf(c[2][1], a2 + b.y);
    c[2][2] = fminf(c[2][2], a2 + b.z); c[2][3] = fminf(c[2][3], a2 + b.w);
    c[3][0] = fminf(c[3][0], a3 + b.x); c[3][1] = fminf(c[3][1], a3 + b.y);
    c[3][2] = fminf(c[3][2], a3 + b.z); c[3][3] = fminf(c[3][3], a3 + b.w);
    int kn = k + 1;
    if (kn < 64) {
      if (kn >= j0 && kn < j0 + 4) {
        int jj = kn - j0;
        Ts[i0 + 0][kn] = sel4(c[0][0], c[0][1], c[0][2], c[0][3], jj);
        Ts[i0 + 1][kn] = sel4(c[1][0], c[1][1], c[1][2], c[1][3], jj);
        Ts[i0 + 2][kn] = sel4(c[2][0], c[2][1], c[2][2], c[2][3], jj);
        Ts[i0 + 3][kn] = sel4(c[3][0], c[3][1], c[3][2], c[3][3], jj);
      }
      if (kn >= i0 && kn < i0 + 4) {
        int ii = kn - i0;
        Ts[kn][j0 + 0] = sel4(c[0][0], c[1][0], c[2][0], c[3][0], ii);
        Ts[kn][j0 + 1] = sel4(c[0][1], c[1][1], c[2][1], c[3][1], ii);
        Ts[kn][j0 + 2] = sel4(c[0][2], c[1][2], c[2][2], c[3][2], ii);
        Ts[kn][j0 + 3] = sel4(c[0][3], c[1][3], c[2][3], c[3][3], ii);
      }
    }
    __syncthreads();
  }
}

// ---------------------------------------------------------------------------
// DATAFLOW FW: one cooperative kernel, 1024 blocks (= tiles), NO grid.sync.
// Cooperative launch guarantees all 1024 blocks co-resident (4/CU by LDS)
// -> flag spins cannot deadlock. Per-tile version flags: state[tile] = number
// of completed rounds whose update required a store (tiles store ONLY when
// entering the round-r cross; bulk p3 rounds live in registers).
// Visibility: producers __threadfence() + release-store flag; consumers spin
// relaxed, then __threadfence() (L1 invalidate). No address is ever re-read
// across rounds (each panel tile is read in exactly one round), so per-XCD L2
// staleness cannot occur.
// ---------------------------------------------------------------------------
__global__ __launch_bounds__(256, 4) void fw_dataflow(
    const float* __restrict__ mg, const float* __restrict__ nw,
    float* __restrict__ d, int* __restrict__ state) {
  __shared__ __align__(16) float As[64][68];
  __shared__ __align__(16) float Bs[64][68];
  const int t = threadIdx.x;
  const int by = blockIdx.x >> 5, bx = blockIdx.x & 31;
  const int tx = t & 15, ty = t >> 4;
  const int i0 = ty * 4, j0 = tx * 4;
  const int obase = (by * 64) * NN + bx * 64;
  const int me = blockIdx.x;

  // ---- build own tile into REGISTERS (transposed part staged via LDS)
  float c[4][4];
  {
#pragma unroll
    for (int l = 0; l < 16; ++l) {
      int idx = l * 256 + t;
      int rr = idx >> 6, cc = idx & 63;
      As[cc][rr] = mg[(bx * 64 + rr) * NN + by * 64 + cc];  // As[il][jl] = mg[j][i]
    }
    __syncthreads();
    float4 nwj = *(const float4*)&nw[bx * 64 + j0];
    float nwj_[4] = {nwj.x, nwj.y, nwj.z, nwj.w};
#pragma unroll
    for (int ii = 0; ii < 4; ++ii) {
      int gi = by * 64 + i0 + ii;
      float nwi = nw[gi];
      float4 av = *(const float4*)&mg[gi * NN + bx * 64 + j0];
      float a_[4] = {av.x, av.y, av.z, av.w};
#pragma unroll
      for (int jj = 0; jj < 4; ++jj) {
        int gj = bx * 64 + j0 + jj;
        float a = a_[jj] * nwi;
        float b = As[i0 + ii][j0 + jj] * nwj_[jj];
        float wa = a > 0.0f ? a : FW_INF;
        float wb = b > 0.0f ? b : FW_INF;
        float v = fminf(wa, wb);
        if (gi == gj) v = 0.0f;
        c[ii][jj] = v;
      }
    }
  }

  for (int r = 0; r < NT; ++r) {
    __syncthreads();                       // guard LDS reuse across rounds
    if (by == r && bx == r) {
      // ---- diagonal: close in LDS, store, release flag (no waits!)
#pragma unroll
      for (int ii = 0; ii < 4; ++ii)
        *(float4*)&As[i0 + ii][j0] =
            make_float4(c[ii][0], c[ii][1], c[ii][2], c[ii][3]);
      __syncthreads();
      close_publish(As, c, i0, j0);
      store_c(d, obase, c, i0, j0);
      __syncthreads();                     // all stores issued before fence
      if (t == 0) {
        __threadfence();
        __hip_atomic_store(&state[me], r + 1, __ATOMIC_RELEASE,
                           __HIP_MEMORY_SCOPE_AGENT);
      }
    } else if (by == r || bx == r) {
      // ---- panel: wait closed diag, apply, store, release flag
      if (t == 0) {
        while (__hip_atomic_load(&state[r * 32 + r], __ATOMIC_RELAXED,
                                 __HIP_MEMORY_SCOPE_AGENT) <= r)
          __builtin_amdgcn_s_sleep(1);
        __threadfence();                   // acquire: invalidate L1
      }
      __syncthreads();
      int dbase = (r * 64) * NN + r * 64;
      if (by == r) {                       // row-panel: C = min(C, diag* (x) C)
        stage_tile(d, dbase, As, t);
#pragma unroll
        for (int ii = 0; ii < 4; ++ii)
          *(float4*)&Bs[i0 + ii][j0] =
              make_float4(c[ii][0], c[ii][1], c[ii][2], c[ii][3]);
      } else {                             // col-panel: C = min(C, C (x) diag*)
        stage_tile(d, dbase, Bs, t);
#pragma unroll
        for (int ii = 0; ii < 4; ++ii)
          *(float4*)&As[i0 + ii][j0] =
              make_float4(c[ii][0], c[ii][1], c[ii][2], c[ii][3]);
      }
      __syncthreads();
      minplus16(As, Bs, c, i0, j0);
      store_c(d, obase, c, i0, j0);
      __syncthreads();
      if (t == 0) {
        __threadfence();
        __hip_atomic_store(&state[me], r + 1, __ATOMIC_RELEASE,
                           __HIP_MEMORY_SCOPE_AGENT);
      }
    } else {
      // ---- bulk p3: wait both panels, stage, minplus; NO store/flag
      if (t == 0) {
        while (__hip_atomic_load(&state[by * 32 + r], __ATOMIC_RELAXED,
                                 __HIP_MEMORY_SCOPE_AGENT) <= r)
          __builtin_amdgcn_s_sleep(1);
        while (__hip_atomic_load(&state[r * 32 + bx], __ATOMIC_RELAXED,
                                 __HIP_MEMORY_SCOPE_AGENT) <= r)
          __builtin_amdgcn_s_sleep(1);
        __threadfence();
      }
      __syncthreads();
      stage_tile(d, (by * 64) * NN + r * 64, As, t);
      stage_tile(d, (r * 64) * NN + bx * 64, Bs, t);
      __syncthreads();
      minplus16(As, Bs, c, i0, j0);
    }
  }
  store_c(d, obase, c, i0, j0);            // final distances for cv_kernel
}

// ---------------------------------------------------------------------------
// Fallback path (only if the cooperative launch is rejected) — R5's proven
// multi-launch structure.
// ---------------------------------------------------------------------------
__device__ __forceinline__ void load_c(const float* __restrict__ g, int base,
                                       float c[4][4], int i0, int j0) {
#pragma unroll
  for (int ii = 0; ii < 4; ++ii) {
    float4 v = *(const float4*)&g[base + (ii + i0) * NN + j0];
    c[ii][0] = v.x; c[ii][1] = v.y; c[ii][2] = v.z; c[ii][3] = v.w;
  }
}

__device__ __forceinline__ void close_in_lds(float (*S)[68], float c[4][4],
                                             int i0, int j0) {
  for (int p = 0; p < 6; ++p) {
    minplus16(S, S, c, i0, j0);
#pragma unroll
    for (int ii = 0; ii < 4; ++ii)
      *(float4*)&S[i0 + ii][j0] = make_float4(c[ii][0], c[ii][1], c[ii][2], c[ii][3]);
    __syncthreads();
  }
}

__global__ __launch_bounds__(256) void build_w_kernel(
    const float* __restrict__ mg, const float* __restrict__ nw,
    float* __restrict__ w) {
  __shared__ float Tt[64][65];
  int bi = blockIdx.y, bj = blockIdx.x;
  int t = threadIdx.x;
#pragma unroll
  for (int l = 0; l < 16; ++l) {
    int idx = l * 256 + t;
    int r = idx >> 6, c = idx & 63;
    Tt[c][r] = mg[(bj * 64 + r) * NN + bi * 64 + c];
  }
  __syncthreads();
#pragma unroll
  for (int l = 0; l < 16; ++l) {
    int idx = l * 256 + t;
    int r = idx >> 6, c = idx & 63;
    int i = bi * 64 + r, j = bj * 64 + c;
    float a = mg[i * NN + j] * nw[i];
    float b = Tt[r][c] * nw[j];
    float wa = a > 0.0f ? a : FW_INF;
    float wb = b > 0.0f ? b : FW_INF;
    float v = fminf(wa, wb);
    if (i == j) v = 0.0f;
    w[i * NN + j] = v;
  }
}

__global__ __launch_bounds__(256) void fw_close0(float* __restrict__ d) {
  __shared__ __align__(16) float As[64][68];
  int t = threadIdx.x;
  int tx = t & 15, ty = t >> 4;
  int i0 = ty * 4, j0 = tx * 4;
  stage_tile(d, 0, As, t);
  __syncthreads();
  float c[4][4];
#pragma unroll
  for (int ii = 0; ii < 4; ++ii) {
    float4 v = *(const float4*)&As[i0 + ii][j0];
    c[ii][0] = v.x; c[ii][1] = v.y; c[ii][2] = v.z; c[ii][3] = v.w;
  }
  close_in_lds(As, c, i0, j0);
  store_c(d, 0, c, i0, j0);
}

__global__ __launch_bounds__(256) void fw_p2(float* __restrict__ d, int r) {
  __shared__ __align__(16) float As[64][68];
  __shared__ __align__(16) float Bs[64][68];
  int t = threadIdx.x;
  int tx = t & 15, ty = t >> 4;
  int i0 = ty * 4, j0 = tx * 4;
  int side = blockIdx.x & 1, idx = blockIdx.x >> 1;
  int tile = idx + (idx >= r);
  int dbase = (r * 64) * NN + r * 64;
  int obase = (side == 0) ? (r * 64) * NN + tile * 64
                          : (tile * 64) * NN + r * 64;
  stage_tile(d, dbase, (side == 0) ? As : Bs, t);
  stage_tile(d, obase, (side == 0) ? Bs : As, t);
  float c[4][4];
  load_c(d, obase, c, i0, j0);
  __syncthreads();
  minplus16(As, Bs, c, i0, j0);
  store_c(d, obase, c, i0, j0);
}

__global__ __launch_bounds__(256) void fw_p3(float* __restrict__ d, int r) {
  __shared__ __align__(16) float As[64][68];
  __shared__ __align__(16) float Bs[64][68];
  int bx = blockIdx.x, by = blockIdx.y;
  if (bx == r || by == r) return;
  int t = threadIdx.x;
  int tx = t & 15, ty = t >> 4;
  int i0 = ty * 4, j0 = tx * 4;
  stage_tile(d, (by * 64) * NN + r * 64, As, t);
  stage_tile(d, (r * 64) * NN + bx * 64, Bs, t);
  int obase = (by * 64) * NN + bx * 64;
  float c[4][4];
  load_c(d, obase, c, i0, j0);
  __syncthreads();
  minplus16(As, Bs, c, i0, j0);
  bool closer = (bx == r + 1) && (by == r + 1) && (r + 1 < NT);
  if (closer) {
    __syncthreads();
#pragma unroll
    for (int ii = 0; ii < 4; ++ii)
      *(float4*)&As[i0 + ii][j0] = make_float4(c[ii][0], c[ii][1], c[ii][2], c[ii][3]);
    __syncthreads();
    close_in_lds(As, c, i0, j0);
  }
  store_c(d, obase, c, i0, j0);
}

// ---------------------------------------------------------------------------
// anchors[rank] = i, rank = #{j: nw[j]>nw[i]} + #{j<i: nw[j]==nw[i]} (stable
// argsort(-nw)). nw staged in LDS, row scan split 4 ways.
// ---------------------------------------------------------------------------
__global__ __launch_bounds__(256) void anchors_kernel(
    const float* __restrict__ nw, int* __restrict__ anchors) {
  __shared__ __align__(16) float s[NN];
  int t = threadIdx.x;
#pragma unroll
  for (int l = 0; l < NN / 256; ++l) s[l * 256 + t] = nw[l * 256 + t];
  __syncthreads();
  int i = blockIdx.x * 64 + (t >> 2);
  int q = t & 3;
  float wi = s[i];
  int rank = 0;
  int jb = q * (NN / 4);
  for (int j = jb; j < jb + NN / 4; j += 4) {
    float4 v = *(const float4*)&s[j];
    rank += (int)(v.x > wi) + ((int)(v.x == wi) & (int)(j + 0 < i));
    rank += (int)(v.y > wi) + ((int)(v.y == wi) & (int)(j + 1 < i));
    rank += (int)(v.z > wi) + ((int)(v.z == wi) & (int)(j + 2 < i));
    rank += (int)(v.w > wi) + ((int)(v.w == wi) & (int)(j + 3 < i));
  }
  rank += __shfl_xor(rank, 1);
  rank += __shfl_xor(rank, 2);
  if (q == 0 && rank < AA) anchors[rank] = i;
}

// ---------------------------------------------------------------------------
// Gather consensus_vectors (inf -> 100), accumulate global sum.
// ---------------------------------------------------------------------------
__global__ __launch_bounds__(256) void cv_kernel(
    const float* __restrict__ dist, const int* __restrict__ anchors,
    float* __restrict__ cv_out, float* __restrict__ sum_acc) {
  int idx = blockIdx.x * 256 + threadIdx.x;   // 800*256 == 204800 exactly
  int i = idx / 100, a = idx - i * 100;
  float dv = dist[i * NN + anchors[a]];
  if (isinf(dv)) dv = 100.0f;
  cv_out[idx] = dv;
  float v = dv;
#pragma unroll
  for (int off = 32; off > 0; off >>= 1) v += __shfl_down(v, off);
  __shared__ float sv[4];
  int lane = threadIdx.x & 63, w = threadIdx.x >> 6;
  if (lane == 0) sv[w] = v;
  __syncthreads();
  if (threadIdx.x == 0) atomicAdd(sum_acc, sv[0] + sv[1] + sv[2] + sv[3]);
}

// ---------------------------------------------------------------------------
// consensus_graph: weighted = wm*cv on the fly; per-row xx in-block; K=100
// f32 dot + RBF epilogue.
// ---------------------------------------------------------------------------
__global__ __launch_bounds__(256) void graph_kernel(
    const float* __restrict__ wm, const float* __restrict__ cv,
    const float* __restrict__ sigma, float* __restrict__ graph) {
  __shared__ __align__(16) float As[64][108];
  __shared__ __align__(16) float Bs[64][108];
  __shared__ float xs[64], ys[64];
  int bx = blockIdx.x, by = blockIdx.y;
  int t = threadIdx.x;
#pragma unroll
  for (int l = 0; l < 7; ++l) {
    int idx = l * 256 + t;
    if (idx < 1600) {                 // 64 rows * 25 float4
      int row = idx / 25, c4 = (idx - row * 25) * 4;
      float4 wa = *(const float4*)&wm[(by * 64 + row) * AA + c4];
      float4 ca = *(const float4*)&cv[(by * 64 + row) * AA + c4];
      *(float4*)&As[row][c4] =
          make_float4(wa.x * ca.x, wa.y * ca.y, wa.z * ca.z, wa.w * ca.w);
      float4 wb = *(const float4*)&wm[(bx * 64 + row) * AA + c4];
      float4 cb = *(const float4*)&cv[(bx * 64 + row) * AA + c4];
      *(float4*)&Bs[row][c4] =
          make_float4(wb.x * cb.x, wb.y * cb.y, wb.z * cb.z, wb.w * cb.w);
    }
  }
  __syncthreads();
  if (t < 64) {
    float s = 0.0f;
    for (int k4 = 0; k4 < 25; ++k4) {
      float4 q = *(const float4*)&As[t][k4 * 4];
      s += q.x * q.x + q.y * q.y + q.z * q.z + q.w * q.w;
    }
    xs[t] = s;
  } else if (t < 128) {
    int r = t - 64;
    float s = 0.0f;
    for (int k4 = 0; k4 < 25; ++k4) {
      float4 q = *(const float4*)&Bs[r][k4 * 4];
      s += q.x * q.x + q.y * q.y + q.z * q.z + q.w * q.w;
    }
    ys[r] = s;
  }
  __syncthreads();
  int tx = t & 15, ty = t >> 4;
  float acc[4][4] = {{0.0f}};
#pragma unroll 5
  for (int k4 = 0; k4 < 25; ++k4) {
    int k = k4 * 4;
    float4 a_[4], b_[4];
#pragma unroll
    for (int ii = 0; ii < 4; ++ii) a_[ii] = *(const float4*)&As[ty + 16 * ii][k];
#pragma unroll
    for (int jj = 0; jj < 4; ++jj) b_[jj] = *(const float4*)&Bs[tx + 16 * jj][k];
#pragma unroll
    for (int ii = 0; ii < 4; ++ii)
#pragma unroll
      for (int jj = 0; jj < 4; ++jj)
        acc[ii][jj] += a_[ii].x * b_[jj].x + a_[ii].y * b_[jj].y +
                       a_[ii].z * b_[jj].z + a_[ii].w * b_[jj].w;
  }
  float s = *sigma;
  float inv2s2 = 0.5f / (s * s);
#pragma unroll
  for (int ii = 0; ii < 4; ++ii) {
    int gi = by * 64 + ty + 16 * ii;
    float xi = xs[ty + 16 * ii];
#pragma unroll
    for (int jj = 0; jj < 4; ++jj) {
      int gj = bx * 64 + tx + 16 * jj;
      float sq = fmaxf(xi + ys[tx + 16 * jj] - 2.0f * acc[ii][jj], 0.0f);
      graph[gi * NN + gj] = __expf(-(sq * sq) * inv2s2);
    }
  }
}

__global__ void finalize_kernel(const float* __restrict__ sum_acc,
                                float* __restrict__ out) {
  if (threadIdx.x == 0)
    *out = (*sum_acc - 204800.0f) / 204800.0f;  // (sum - N*100) / (N*A)
}

// ---------------------------------------------------------------------------
extern "C" void kernel_launch(void* const* d_in, const int* in_sizes, int n_in,
                              void* d_out, int out_size, void* d_ws, size_t ws_size,
                              hipStream_t stream) {
  (void)in_sizes; (void)n_in; (void)out_size;
  const float* mg    = (const float*)d_in[0];
  const float* nw    = (const float*)d_in[1];
  const float* wm    = (const float*)d_in[2];
  const float* sigma = (const float*)d_in[3];
  float* out        = (float*)d_out;
  float* cv_out     = out;            // 2048*100
  float* scalar_out = out + 204800;   // 1
  float* graph_out  = out + 204801;   // 2048*2048

  float* W = (float*)d_ws;
  float* sum_acc = W;                 // 1 float
  int* anchors   = (int*)(W + 4);     // 100 ints @ W[4..104)
  int* state     = (int*)(W + 128);   // 1024 ints @ W[128..1152)
  float* dist;
  if (ws_size >= (size_t)(1536 + (size_t)NN * NN) * sizeof(float)) {
    dist = W + 1536;                  // 16 MB scratch, 16B-aligned
  } else {
    // Alias dist onto out+204800 (16B-aligned). cv_kernel extracts anchor
    // columns BEFORE graph_kernel overwrites; finalize writes scalar LAST.
    dist = out + 204800;
  }

  hipMemsetAsync(sum_acc, 0, sizeof(float), stream);
  hipMemsetAsync(state, 0, NT * NT * sizeof(int), stream);

  void* kargs[] = {(void*)&mg, (void*)&nw, (void*)&dist, (void*)&state};
  hipError_t ce = hipLaunchCooperativeKernel((const void*)fw_dataflow,
                                             dim3(NT * NT), dim3(256), kargs,
                                             0, stream);
  if (ce != hipSuccess) {
    // Fallback: proven multi-launch blocked FW (identical math).
    build_w_kernel<<<dim3(NT, NT), 256, 0, stream>>>(mg, nw, dist);
    fw_close0<<<1, 256, 0, stream>>>(dist);
    for (int r = 0; r < NT; ++r) {
      fw_p2<<<62, 256, 0, stream>>>(dist, r);
      fw_p3<<<dim3(NT, NT), 256, 0, stream>>>(dist, r);
    }
  }

  anchors_kernel<<<NN / 64, 256, 0, stream>>>(nw, anchors);
  cv_kernel<<<800, 256, 0, stream>>>(dist, anchors, cv_out, sum_acc);
  graph_kernel<<<dim3(NT, NT), 256, 0, stream>>>(wm, cv_out, sigma, graph_out);
  finalize_kernel<<<1, 64, 0, stream>>>(sum_acc, scalar_out);
}

// Round 8
// 1454.619 us; speedup vs baseline: 5.2025x; 1.8782x over previous
//
#include <hip/hip_runtime.h>

// Problem constants (reference: N=2048, A=100)
#define NN 2048
#define AA 100
#define NT 32   // 64-wide tiles per side (2048/64)
#define FW_INF __builtin_huge_valf()

// ---------------------------------------------------------------------------
// 64-tile helpers (LDS rows padded to 68). dist is ALWAYS 16B-aligned.
// ---------------------------------------------------------------------------
__device__ __forceinline__ void stage_tile(const float* __restrict__ g, int base,
                                           float (*S)[68], int t) {
#pragma unroll
  for (int l = 0; l < 4; ++l) {
    int i4 = l * 256 + t;                   // 64 rows x 16 float4
    int row = i4 >> 4, c4 = (i4 & 15) << 2;
    *(float4*)&S[row][c4] = *(const float4*)&g[base + row * NN + c4];
  }
}

__device__ __forceinline__ void load_c(const float* __restrict__ g, int base,
                                       float c[4][4], int i0, int j0) {
#pragma unroll
  for (int ii = 0; ii < 4; ++ii) {
    float4 v = *(const float4*)&g[base + (i0 + ii) * NN + j0];
    c[ii][0] = v.x; c[ii][1] = v.y; c[ii][2] = v.z; c[ii][3] = v.w;
  }
}

__device__ __forceinline__ void store_c(float* __restrict__ g, int base,
                                        const float c[4][4], int i0, int j0) {
#pragma unroll
  for (int ii = 0; ii < 4; ++ii)
    *(float4*)&g[base + (i0 + ii) * NN + j0] =
        make_float4(c[ii][0], c[ii][1], c[ii][2], c[ii][3]);
}

// k4 min-plus inner loop (4x4 micro): c = min(c, A (x) B), k=0..63.
__device__ __forceinline__ void minplus16(const float (*A)[68], const float (*B)[68],
                                          float c[4][4], int i0, int j0) {
#pragma unroll 4
  for (int k4 = 0; k4 < 16; ++k4) {
    const int k = k4 * 4;
    float4 a0 = *(const float4*)&A[i0 + 0][k];
    float4 a1 = *(const float4*)&A[i0 + 1][k];
    float4 a2 = *(const float4*)&A[i0 + 2][k];
    float4 a3 = *(const float4*)&A[i0 + 3][k];
    float4 b0 = *(const float4*)&B[k + 0][j0];
    float4 b1 = *(const float4*)&B[k + 1][j0];
    float4 b2 = *(const float4*)&B[k + 2][j0];
    float4 b3 = *(const float4*)&B[k + 3][j0];
#define MP_ROW(ii)                                                                        \
    c[ii][0] = fminf(c[ii][0], fminf(fminf(a##ii.x + b0.x, a##ii.y + b1.x),               \
                                     fminf(a##ii.z + b2.x, a##ii.w + b3.x)));             \
    c[ii][1] = fminf(c[ii][1], fminf(fminf(a##ii.x + b0.y, a##ii.y + b1.y),               \
                                     fminf(a##ii.z + b2.y, a##ii.w + b3.y)));             \
    c[ii][2] = fminf(c[ii][2], fminf(fminf(a##ii.x + b0.z, a##ii.y + b1.z),               \
                                     fminf(a##ii.z + b2.z, a##ii.w + b3.z)));             \
    c[ii][3] = fminf(c[ii][3], fminf(fminf(a##ii.x + b0.w, a##ii.y + b1.w),               \
                                     fminf(a##ii.z + b2.w, a##ii.w + b3.w)))
    MP_ROW(0); MP_ROW(1); MP_ROW(2); MP_ROW(3);
#undef MP_ROW
  }
}

// In-place transitive closure of the 64x64 tile in S (c == S's (i0,j0) block,
// staged & barriered by caller). 6 in-place min-plus squaring passes:
// min-monotone mid-pass races are safe (4B LDS atomicity; every value is a
// real path length, only decreases); 6 passes == closure (2^6 >= 64).
__device__ __forceinline__ void close_in_lds(float (*S)[68], float c[4][4],
                                             int i0, int j0) {
  for (int p = 0; p < 6; ++p) {
    minplus16(S, S, c, i0, j0);
#pragma unroll
    for (int ii = 0; ii < 4; ++ii)
      *(float4*)&S[i0 + ii][j0] = make_float4(c[ii][0], c[ii][1], c[ii][2], c[ii][3]);
    __syncthreads();
  }
}

// ---------------------------------------------------------------------------
// build w[i][j] = min(f(mg[i][j]*nw[i]), f(mg[j][i]*nw[j])), f(x)=x>0?x:inf,
// diag=0. Transpose element via LDS tile for coalescing.
// ---------------------------------------------------------------------------
__global__ __launch_bounds__(256) void build_w_kernel(
    const float* __restrict__ mg, const float* __restrict__ nw,
    float* __restrict__ w) {
  __shared__ float Tt[64][65];
  int bi = blockIdx.y, bj = blockIdx.x;
  int t = threadIdx.x;
#pragma unroll
  for (int l = 0; l < 16; ++l) {
    int idx = l * 256 + t;
    int r = idx >> 6, c = idx & 63;
    Tt[c][r] = mg[(bj * 64 + r) * NN + bi * 64 + c];
  }
  __syncthreads();
#pragma unroll
  for (int l = 0; l < 16; ++l) {
    int idx = l * 256 + t;
    int r = idx >> 6, c = idx & 63;
    int i = bi * 64 + r, j = bj * 64 + c;
    float a = mg[i * NN + j] * nw[i];
    float b = Tt[r][c] * nw[j];
    float wa = a > 0.0f ? a : FW_INF;
    float wb = b > 0.0f ? b : FW_INF;
    float v = fminf(wa, wb);
    if (i == j) v = 0.0f;
    w[i * NN + j] = v;
  }
}

// Standalone closure of tile (0,0) — once before round 0.
__global__ __launch_bounds__(256) void fw_close0(float* __restrict__ d) {
  __shared__ __align__(16) float As[64][68];
  int t = threadIdx.x;
  int tx = t & 15, ty = t >> 4;
  int i0 = ty * 4, j0 = tx * 4;
  stage_tile(d, 0, As, t);
  __syncthreads();
  float c[4][4];
#pragma unroll
  for (int ii = 0; ii < 4; ++ii) {
    float4 v = *(const float4*)&As[i0 + ii][j0];
    c[ii][0] = v.x; c[ii][1] = v.y; c[ii][2] = v.z; c[ii][3] = v.w;
  }
  close_in_lds(As, c, i0, j0);
  store_c(d, 0, c, i0, j0);
}

// ---------------------------------------------------------------------------
// Phase 2: diag (r,r) is ALREADY closed in global (closer of prev round /
// fw_close0). 62 blocks: side 0: C(r,t)=min(C, diag* (x) C); side 1:
// C(t,r)=min(C, C (x) diag*). One-pass in-place valid (diag closed).
// ---------------------------------------------------------------------------
__global__ __launch_bounds__(256) void fw_p2(float* __restrict__ d, int r) {
  __shared__ __align__(16) float As[64][68];
  __shared__ __align__(16) float Bs[64][68];
  int t = threadIdx.x;
  int tx = t & 15, ty = t >> 4;
  int i0 = ty * 4, j0 = tx * 4;
  int side = blockIdx.x & 1, idx = blockIdx.x >> 1;
  int tile = idx + (idx >= r);
  int dbase = (r * 64) * NN + r * 64;
  int obase = (side == 0) ? (r * 64) * NN + tile * 64
                          : (tile * 64) * NN + r * 64;
  stage_tile(d, dbase, (side == 0) ? As : Bs, t);
  stage_tile(d, obase, (side == 0) ? Bs : As, t);
  float c[4][4];
  load_c(d, obase, c, i0, j0);
  __syncthreads();
  minplus16(As, Bs, c, i0, j0);
  store_c(d, obase, c, i0, j0);
}

// ---------------------------------------------------------------------------
// Phase 3: grid = 257 blocks.
//   Blocks 0..255: 128x128 output tile (BY,BX), 8x8 register micro-tile,
//     A-panel staged TRANSPOSED (AsT[k][i]) so a-frags are b128 broadcasts.
//     VALU-bound: 128 VALU vs ~48 LDS-issue cyc per wave per k.
//     Skip stores for 64-subtiles on the round-r cross (owned by p2) and for
//     (r+1,r+1) (owned by the closer).
//   Block 256: dedicated closer — computes the (r+1,r+1) 64-subtile p3 update
//     and its transitive closure CONCURRENTLY with the bulk, stores closed.
// ---------------------------------------------------------------------------
__global__ __launch_bounds__(256) void fw_p3(float* __restrict__ d, int r) {
  __shared__ __align__(16) float AsT[64][132];   // A^T: AsT[k][i], i=0..127
  __shared__ __align__(16) float Bs2[64][132];   // B:   Bs2[k][j], j=0..127
  const int t = threadIdx.x;
  const int rp = r + 1;

  if (blockIdx.x == 256) {
    // ---- dedicated closer
    if (rp >= NT) return;
    float (*Ta)[68] = (float(*)[68])&AsT[0][0];
    float (*Tb)[68] = (float(*)[68])&Bs2[0][0];
    const int tx = t & 15, ty = t >> 4;
    const int i0 = ty * 4, j0 = tx * 4;
    stage_tile(d, (rp * 64) * NN + r * 64, Ta, t);   // A64(rp, r)  post-p2
    stage_tile(d, (r * 64) * NN + rp * 64, Tb, t);   // B64(r, rp)  post-p2
    const int obase = (rp * 64) * NN + rp * 64;
    float c[4][4];
    load_c(d, obase, c, i0, j0);
    __syncthreads();
    minplus16(Ta, Tb, c, i0, j0);
    __syncthreads();                                 // panel reads done
#pragma unroll
    for (int ii = 0; ii < 4; ++ii)
      *(float4*)&Ta[i0 + ii][j0] = make_float4(c[ii][0], c[ii][1], c[ii][2], c[ii][3]);
    __syncthreads();
    close_in_lds(Ta, c, i0, j0);
    store_c(d, obase, c, i0, j0);
    return;
  }

  const int BY = blockIdx.x >> 4, BX = blockIdx.x & 15;
  const int tx = t & 15, ty = t >> 4;
  const int i0 = ty * 8, j0 = tx * 8;   // 8x8 micro-tile
  const int gr = BY * 128, gc = BX * 128;

  // ---- stage A panel transposed: rows [gr,+128) x cols [64r,+64) -> AsT[k][i]
#pragma unroll
  for (int l = 0; l < 8; ++l) {
    int idx = l * 256 + t;              // 0..2047 = 128 rows x 16 float4
    int row = idx >> 4, kc = (idx & 15) << 2;
    float4 v = *(const float4*)&d[(gr + row) * NN + r * 64 + kc];
    AsT[kc + 0][row] = v.x; AsT[kc + 1][row] = v.y;
    AsT[kc + 2][row] = v.z; AsT[kc + 3][row] = v.w;
  }
  // ---- stage B panel: rows [64r,+64) x cols [gc,+128) -> Bs2[k][j]
#pragma unroll
  for (int l = 0; l < 8; ++l) {
    int idx = l * 256 + t;              // 0..2047 = 64 rows x 32 float4
    int row = idx >> 5, jc = (idx & 31) << 2;
    *(float4*)&Bs2[row][jc] = *(const float4*)&d[(r * 64 + row) * NN + gc + jc];
  }

  // ---- init C micro-tile from global
  float c[8][8];
#pragma unroll
  for (int ii = 0; ii < 8; ++ii) {
    float4 v0 = *(const float4*)&d[(gr + i0 + ii) * NN + gc + j0];
    float4 v1 = *(const float4*)&d[(gr + i0 + ii) * NN + gc + j0 + 4];
    c[ii][0] = v0.x; c[ii][1] = v0.y; c[ii][2] = v0.z; c[ii][3] = v0.w;
    c[ii][4] = v1.x; c[ii][5] = v1.y; c[ii][6] = v1.z; c[ii][7] = v1.w;
  }
  __syncthreads();

  // ---- min-plus K-loop (VALU-bound: 128 VALU / 4 b128 per k per thread)
#pragma unroll 2
  for (int k = 0; k < 64; ++k) {
    float4 aL = *(const float4*)&AsT[k][i0];
    float4 aH = *(const float4*)&AsT[k][i0 + 4];
    float4 bL = *(const float4*)&Bs2[k][j0];
    float4 bH = *(const float4*)&Bs2[k][j0 + 4];
    float av[8] = {aL.x, aL.y, aL.z, aL.w, aH.x, aH.y, aH.z, aH.w};
    float bv[8] = {bL.x, bL.y, bL.z, bL.w, bH.x, bH.y, bH.z, bH.w};
#pragma unroll
    for (int ii = 0; ii < 8; ++ii)
#pragma unroll
      for (int jj = 0; jj < 8; ++jj)
        c[ii][jj] = fminf(c[ii][jj], av[ii] + bv[jj]);
  }

  // ---- store (8x8 micro lies entirely inside ONE 64-subtile: single predicate)
  const int r64 = (gr + i0) >> 6;
  const int c64 = (gc + j0) >> 6;
  bool skip = (r64 == r) || (c64 == r) || (rp < NT && r64 == rp && c64 == rp);
  if (!skip) {
#pragma unroll
    for (int ii = 0; ii < 8; ++ii) {
      *(float4*)&d[(gr + i0 + ii) * NN + gc + j0] =
          make_float4(c[ii][0], c[ii][1], c[ii][2], c[ii][3]);
      *(float4*)&d[(gr + i0 + ii) * NN + gc + j0 + 4] =
          make_float4(c[ii][4], c[ii][5], c[ii][6], c[ii][7]);
    }
  }
}

// ---------------------------------------------------------------------------
// anchors[rank] = i, rank = #{j: nw[j]>nw[i]} + #{j<i: nw[j]==nw[i]} (stable
// argsort(-nw)). nw staged in LDS, row scan split 4 ways.
// ---------------------------------------------------------------------------
__global__ __launch_bounds__(256) void anchors_kernel(
    const float* __restrict__ nw, int* __restrict__ anchors) {
  __shared__ __align__(16) float s[NN];
  int t = threadIdx.x;
#pragma unroll
  for (int l = 0; l < NN / 256; ++l) s[l * 256 + t] = nw[l * 256 + t];
  __syncthreads();
  int i = blockIdx.x * 64 + (t >> 2);
  int q = t & 3;
  float wi = s[i];
  int rank = 0;
  int jb = q * (NN / 4);
  for (int j = jb; j < jb + NN / 4; j += 4) {
    float4 v = *(const float4*)&s[j];
    rank += (int)(v.x > wi) + ((int)(v.x == wi) & (int)(j + 0 < i));
    rank += (int)(v.y > wi) + ((int)(v.y == wi) & (int)(j + 1 < i));
    rank += (int)(v.z > wi) + ((int)(v.z == wi) & (int)(j + 2 < i));
    rank += (int)(v.w > wi) + ((int)(v.w == wi) & (int)(j + 3 < i));
  }
  rank += __shfl_xor(rank, 1);
  rank += __shfl_xor(rank, 2);
  if (q == 0 && rank < AA) anchors[rank] = i;
}

// ---------------------------------------------------------------------------
// Gather consensus_vectors (inf -> 100), accumulate global sum.
// ---------------------------------------------------------------------------
__global__ __launch_bounds__(256) void cv_kernel(
    const float* __restrict__ dist, const int* __restrict__ anchors,
    float* __restrict__ cv_out, float* __restrict__ sum_acc) {
  int idx = blockIdx.x * 256 + threadIdx.x;   // 800*256 == 204800 exactly
  int i = idx / 100, a = idx - i * 100;
  float dv = dist[i * NN + anchors[a]];
  if (isinf(dv)) dv = 100.0f;
  cv_out[idx] = dv;
  float v = dv;
#pragma unroll
  for (int off = 32; off > 0; off >>= 1) v += __shfl_down(v, off);
  __shared__ float sv[4];
  int lane = threadIdx.x & 63, w = threadIdx.x >> 6;
  if (lane == 0) sv[w] = v;
  __syncthreads();
  if (threadIdx.x == 0) atomicAdd(sum_acc, sv[0] + sv[1] + sv[2] + sv[3]);
}

// ---------------------------------------------------------------------------
// consensus_graph: weighted = wm*cv on the fly; per-row xx in-block; K=100
// f32 dot + RBF epilogue.
// ---------------------------------------------------------------------------
__global__ __launch_bounds__(256) void graph_kernel(
    const float* __restrict__ wm, const float* __restrict__ cv,
    const float* __restrict__ sigma, float* __restrict__ graph) {
  __shared__ __align__(16) float As[64][108];
  __shared__ __align__(16) float Bs[64][108];
  __shared__ float xs[64], ys[64];
  int bx = blockIdx.x, by = blockIdx.y;
  int t = threadIdx.x;
#pragma unroll
  for (int l = 0; l < 7; ++l) {
    int idx = l * 256 + t;
    if (idx < 1600) {                 // 64 rows * 25 float4
      int row = idx / 25, c4 = (idx - row * 25) * 4;
      float4 wa = *(const float4*)&wm[(by * 64 + row) * AA + c4];
      float4 ca = *(const float4*)&cv[(by * 64 + row) * AA + c4];
      *(float4*)&As[row][c4] =
          make_float4(wa.x * ca.x, wa.y * ca.y, wa.z * ca.z, wa.w * ca.w);
      float4 wb = *(const float4*)&wm[(bx * 64 + row) * AA + c4];
      float4 cb = *(const float4*)&cv[(bx * 64 + row) * AA + c4];
      *(float4*)&Bs[row][c4] =
          make_float4(wb.x * cb.x, wb.y * cb.y, wb.z * cb.z, wb.w * cb.w);
    }
  }
  __syncthreads();
  if (t < 64) {
    float s = 0.0f;
    for (int k4 = 0; k4 < 25; ++k4) {
      float4 q = *(const float4*)&As[t][k4 * 4];
      s += q.x * q.x + q.y * q.y + q.z * q.z + q.w * q.w;
    }
    xs[t] = s;
  } else if (t < 128) {
    int r = t - 64;
    float s = 0.0f;
    for (int k4 = 0; k4 < 25; ++k4) {
      float4 q = *(const float4*)&Bs[r][k4 * 4];
      s += q.x * q.x + q.y * q.y + q.z * q.z + q.w * q.w;
    }
    ys[r] = s;
  }
  __syncthreads();
  int tx = t & 15, ty = t >> 4;
  float acc[4][4] = {{0.0f}};
#pragma unroll 5
  for (int k4 = 0; k4 < 25; ++k4) {
    int k = k4 * 4;
    float4 a_[4], b_[4];
#pragma unroll
    for (int ii = 0; ii < 4; ++ii) a_[ii] = *(const float4*)&As[ty + 16 * ii][k];
#pragma unroll
    for (int jj = 0; jj < 4; ++jj) b_[jj] = *(const float4*)&Bs[tx + 16 * jj][k];
#pragma unroll
    for (int ii = 0; ii < 4; ++ii)
#pragma unroll
      for (int jj = 0; jj < 4; ++jj)
        acc[ii][jj] += a_[ii].x * b_[jj].x + a_[ii].y * b_[jj].y +
                       a_[ii].z * b_[jj].z + a_[ii].w * b_[jj].w;
  }
  float s = *sigma;
  float inv2s2 = 0.5f / (s * s);
#pragma unroll
  for (int ii = 0; ii < 4; ++ii) {
    int gi = by * 64 + ty + 16 * ii;
    float xi = xs[ty + 16 * ii];
#pragma unroll
    for (int jj = 0; jj < 4; ++jj) {
      int gj = bx * 64 + tx + 16 * jj;
      float sq = fmaxf(xi + ys[tx + 16 * jj] - 2.0f * acc[ii][jj], 0.0f);
      graph[gi * NN + gj] = __expf(-(sq * sq) * inv2s2);
    }
  }
}

__global__ void finalize_kernel(const float* __restrict__ sum_acc,
                                float* __restrict__ out) {
  if (threadIdx.x == 0)
    *out = (*sum_acc - 204800.0f) / 204800.0f;  // (sum - N*100) / (N*A)
}

// ---------------------------------------------------------------------------
extern "C" void kernel_launch(void* const* d_in, const int* in_sizes, int n_in,
                              void* d_out, int out_size, void* d_ws, size_t ws_size,
                              hipStream_t stream) {
  (void)in_sizes; (void)n_in; (void)out_size;
  const float* mg    = (const float*)d_in[0];
  const float* nw    = (const float*)d_in[1];
  const float* wm    = (const float*)d_in[2];
  const float* sigma = (const float*)d_in[3];
  float* out        = (float*)d_out;
  float* cv_out     = out;            // 2048*100
  float* scalar_out = out + 204800;   // 1
  float* graph_out  = out + 204801;   // 2048*2048

  float* W = (float*)d_ws;
  float* sum_acc = W;                 // 1 float
  int* anchors   = (int*)(W + 4);     // 100 ints
  float* dist;
  if (ws_size >= (size_t)(256 + (size_t)NN * NN) * sizeof(float)) {
    dist = W + 256;                   // 16 MB scratch, 16B-aligned
  } else {
    // Alias dist onto out+204800 (16B-aligned: 204800*4 % 16 == 0). cv_kernel
    // extracts anchor columns BEFORE graph_kernel overwrites; finalize writes
    // the scalar LAST.
    dist = out + 204800;
  }

  hipMemsetAsync(sum_acc, 0, sizeof(float), stream);

  build_w_kernel<<<dim3(NT, NT), 256, 0, stream>>>(mg, nw, dist);
  fw_close0<<<1, 256, 0, stream>>>(dist);
  for (int r = 0; r < NT; ++r) {
    fw_p2<<<62, 256, 0, stream>>>(dist, r);
    fw_p3<<<257, 256, 0, stream>>>(dist, r);
  }

  anchors_kernel<<<NN / 64, 256, 0, stream>>>(nw, anchors);
  cv_kernel<<<800, 256, 0, stream>>>(dist, anchors, cv_out, sum_acc);
  graph_kernel<<<dim3(NT, NT), 256, 0, stream>>>(wm, cv_out, sigma, graph_out);
  finalize_kernel<<<1, 64, 0, stream>>>(sum_acc, scalar_out);
}